// Round 1
// baseline (293.081 us; speedup 1.0000x reference)
//
#include <hip/hip_runtime.h>
#include <hip/hip_bf16.h>
#include <stdint.h>
#include <stddef.h>

// Problem constants
#define BATCH   4096
#define INDIM   512
#define OUTDIM  512
#define NH      32
#define KKDIM   64                 // 2*NH k-values per input dim
#define INV2PI  0.15915494309189535f

// Main-kernel tiling
#define BM       128
#define BN       256
#define THREADS  512
#define KSPLIT   4
#define DIMS_PER_WG (INDIM / KSPLIT)   // 128 input dims per workgroup
#define CHUNK_ELEMS (BN * KKDIM)       // 16384 bf16 = 32 KB per (colblock, dim) chunk

// LDS layout (bytes)
#define B_BYTES   32768                       // [256 col][64 kk] bf16, xor-swizzled
#define A_STRIDE  72                          // bf16 per row (64 + 8 pad -> bank-uniform b128 reads)
#define A_BYTES   (BM * A_STRIDE * 2)         // 18432
#define OFF_A0    (2 * B_BYTES)               // 65536
#define OFF_X     (OFF_A0 + 2 * A_BYTES)      // 102400; 2 x-chunks of [8 dims][128 rows] f32
#define SMEM_BYTES (OFF_X + 2 * 8 * 128 * 4)  // 110592

typedef short  bhalf8  __attribute__((ext_vector_type(8)));  // 8 bf16 (4 VGPRs), per guide §3
typedef float  vfloat4 __attribute__((ext_vector_type(4)));

__device__ __forceinline__ unsigned pack_bf16(float a, float b) {
    union { __hip_bfloat162 h2; unsigned u; } cv;
    cv.h2 = __float22bfloat162_rn(float2{a, b});   // cos in low half (kk even), sin in high
    return cv.u;
}

__device__ __forceinline__ void async_copy16(const void* gsrc, void* ldst) {
    __builtin_amdgcn_global_load_lds(
        (const __attribute__((address_space(1))) void*)(uintptr_t)gsrc,
        (__attribute__((address_space(3))) void*)(uint32_t)(uintptr_t)ldst,
        16, 0, 0);
}

// ---------------------------------------------------------------------------
// Prepass: fourier_coeffs fp32 [512,32,2,512] -> bf16 tiles in ws.
// Chunk (cb, i) is 32 KB: [col 0..255][kk 0..63] with 16B-unit swizzle
// pc = (kk>>3) ^ (col&7) baked in, so the main kernel's global_load_lds image
// is exactly the LDS layout its MFMA fragment reads expect.
// ---------------------------------------------------------------------------
__global__ __launch_bounds__(256) void fkan_prepass(const float* __restrict__ coeffs,
                                                    unsigned short* __restrict__ Bt) {
    const int t  = threadIdx.x;
    const int cb = blockIdx.x & 1;
    const int i  = blockIdx.x >> 1;
    const float* __restrict__ src = coeffs + (size_t)i * (KKDIM * OUTDIM) + cb * BN;
    unsigned short* __restrict__ chunk = Bt + (size_t)(cb * INDIM + i) * CHUNK_ELEMS;
#pragma unroll
    for (int s = 0; s < 8; ++s) {
        const int unit = t + s * 256;          // 2048 16B-units per chunk
        const int col  = unit >> 3;
        const int pc   = unit & 7;             // physical 16B slot in this col's row
        const int kb   = (pc ^ (col & 7)) * 8; // logical kk base held in this slot
        const float* p0 = src + (size_t)kb * OUTDIM + col;
        uint4 o;
        o.x = pack_bf16(p0[0 * OUTDIM], p0[1 * OUTDIM]);
        o.y = pack_bf16(p0[2 * OUTDIM], p0[3 * OUTDIM]);
        o.z = pack_bf16(p0[4 * OUTDIM], p0[5 * OUTDIM]);
        o.w = pack_bf16(p0[6 * OUTDIM], p0[7 * OUTDIM]);
        ((uint4*)chunk)[unit] = o;             // lane-contiguous coalesced store
    }
}

// out[b,o] = bias[o]
__global__ __launch_bounds__(256) void fkan_bias_init(const float* __restrict__ bias,
                                                      float* __restrict__ out) {
    const int idx = blockIdx.x * 256 + threadIdx.x;       // 524288 float4s
    ((float4*)out)[idx] = ((const float4*)bias)[idx & 127];
}

// ---------------------------------------------------------------------------
// Main fused kernel helpers
// ---------------------------------------------------------------------------
__device__ __forceinline__ void stage_B(const unsigned short* __restrict__ Bt, char* smem,
                                        int cb, int dim_global, int parity, int t) {
    const char* chunk = (const char*)(Bt + (size_t)(cb * INDIM + dim_global) * CHUNK_ELEMS);
    char* bdst = smem + parity * B_BYTES;
#pragma unroll
    for (int s = 0; s < 4; ++s) {
        const int unit = t + s * 512;
        async_copy16(chunk + unit * 16, bdst + unit * 16);  // dest = wave base + lane*16
    }
}

__device__ __forceinline__ void stage_x(const float* __restrict__ x, char* smem,
                                        int rowbase, int dimbase, int cn, int t) {
    const int r  = t >> 2;
    const int d0 = (t & 3) * 2;
    const float2 xv = *(const float2*)(x + (size_t)(rowbase + r) * INDIM + dimbase + cn * 8 + d0);
    float* xr = (float*)(smem + OFF_X + (cn & 1) * 4096);  // [8][128] f32
    xr[(d0 + 0) * 128 + r] = xv.x * INV2PI;                // store revolutions
    xr[(d0 + 1) * 128 + r] = xv.y * INV2PI;
}

// Compute cos/sin(k*x) for 8 harmonics via complex recurrence, pack bf16 pairs
// into A_lds[row][kk] (kk = 2*(k-1)+{0:cos,1:sin}), padded stride 72.
__device__ __forceinline__ void do_trig(char* smem, int dim_local, int parity, int trow, int tq) {
    const float rv = ((const float*)(smem + OFF_X + ((dim_local >> 3) & 1) * 4096))
                     [(dim_local & 7) * 128 + trow];
    const float cd = __builtin_amdgcn_cosf(rv);   // step e^{i*x} (revolution domain)
    const float sd = __builtin_amdgcn_sinf(rv);
    const float a0 = (float)(tq * 8 + 1) * rv;    // base harmonic k0 = tq*8+1
    float c = __builtin_amdgcn_cosf(a0);
    float s = __builtin_amdgcn_sinf(a0);
    unsigned pk[8];
    pk[0] = pack_bf16(c, s);
#pragma unroll
    for (int j = 1; j < 8; ++j) {
        const float nc = c * cd - s * sd;
        const float ns = s * cd + c * sd;
        c = nc; s = ns;
        pk[j] = pack_bf16(c, s);
    }
    uint4* adst = (uint4*)(smem + OFF_A0 + parity * A_BYTES + trow * (A_STRIDE * 2) + tq * 32);
    uint4 w0; w0.x = pk[0]; w0.y = pk[1]; w0.z = pk[2]; w0.w = pk[3];
    uint4 w1; w1.x = pk[4]; w1.y = pk[5]; w1.z = pk[6]; w1.w = pk[7];
    adst[0] = w0;
    adst[1] = w1;
}

// ---------------------------------------------------------------------------
// Main kernel: grid 256 (= 32 rowblocks x 2 colblocks x 4 ksplits), 512 thr.
// blockIdx&7 -> (colblock, ksplit) group: one group per XCD, whose 4MB bf16
// B-chunk fits that XCD's L2 exactly.
// ---------------------------------------------------------------------------
__global__ __launch_bounds__(THREADS, 2) void fkan_main(const float* __restrict__ x,
                                                        const unsigned short* __restrict__ Bt,
                                                        float* __restrict__ out) {
    __shared__ char smem[SMEM_BYTES];
    const int t      = threadIdx.x;
    const int grp    = blockIdx.x & 7;
    const int member = blockIdx.x >> 3;
    const int cb      = grp & 1;
    const int kq      = grp >> 1;
    const int rowbase = member * BM;
    const int colbase = cb * BN;
    const int dimbase = kq * DIMS_PER_WG;

    const int lane = t & 63;
    const int w    = t >> 6;
    const int wr   = w >> 2;       // wave grid 2 rows x 4 cols; wave tile 64x64
    const int wc   = w & 3;
    const int fr   = lane & 15;    // row/col within 16x16 tile
    const int fq   = lane >> 4;    // quad -> k-chunk of 8
    const int fx   = lane & 7;     // xor swizzle key (== col&7 since tiles are 16-aligned)

    const int trow = t & 127;      // trig: 4 threads per row, 8 harmonics each
    const int tq   = t >> 7;

    vfloat4 acc[4][4];
#pragma unroll
    for (int a = 0; a < 4; ++a)
#pragma unroll
        for (int b = 0; b < 4; ++b) acc[a][b] = (vfloat4)0.0f;

    // Prologue: x chunk 0, then B+A for dim 0 into buffer 0.
    stage_x(x, smem, rowbase, dimbase, 0, t);
    __syncthreads();
    stage_B(Bt, smem, cb, dimbase + 0, 0, t);
    do_trig(smem, 0, 0, trow, tq);
    __syncthreads();

#pragma unroll 2
    for (int it = 0; it < DIMS_PER_WG; ++it) {
        const int p    = it & 1;
        const int inxt = it + 1;
        if (inxt < DIMS_PER_WG) {
            stage_B(Bt, smem, cb, dimbase + inxt, inxt & 1, t);   // async, fills 1-p
            if ((it & 7) == 0) {
                const int cn = (it >> 3) + 1;                     // stage x one chunk ahead
                if (cn < 16) stage_x(x, smem, rowbase, dimbase, cn, t);
            }
            do_trig(smem, inxt, inxt & 1, trow, tq);              // VALU, overlaps MFMA
        }
        // Compute on buffer p
        {
            const char* Ab = smem + OFF_A0 + p * A_BYTES;
            const char* Bb = smem + p * B_BYTES;
#pragma unroll
            for (int ks = 0; ks < 2; ++ks) {
                bhalf8 av[4], bv[4];
#pragma unroll
                for (int rt = 0; rt < 4; ++rt)
                    av[rt] = *(const bhalf8*)(Ab + (wr * 64 + rt * 16 + fr) * (A_STRIDE * 2)
                                                 + ks * 64 + fq * 16);
#pragma unroll
                for (int ct = 0; ct < 4; ++ct)
                    bv[ct] = *(const bhalf8*)(Bb + (wc * 64 + ct * 16 + fr) * 128
                                                 + (((ks * 4 + fq) ^ fx) * 16));
#pragma unroll
                for (int rt = 0; rt < 4; ++rt)
#pragma unroll
                    for (int ct = 0; ct < 4; ++ct)
                        acc[rt][ct] = __builtin_amdgcn_mfma_f32_16x16x32_bf16(
                            av[rt], bv[ct], acc[rt][ct], 0, 0, 0);
            }
        }
        __syncthreads();
    }

    // Epilogue: C/D layout col=lane&15, row=quad*4+reg (m89). KSPLIT partials via atomics.
#pragma unroll
    for (int rt = 0; rt < 4; ++rt) {
#pragma unroll
        for (int ct = 0; ct < 4; ++ct) {
            const int col  = colbase + wc * 64 + ct * 16 + fr;
            const int row0 = rowbase + wr * 64 + rt * 16 + fq * 4;
#pragma unroll
            for (int r = 0; r < 4; ++r)
                atomicAdd(out + (size_t)(row0 + r) * OUTDIM + col, acc[rt][ct][r]);
        }
    }
}

// ---------------------------------------------------------------------------
// Fallback (only if ws too small for the 32MB bf16 B): slow but correct fp32.
// ---------------------------------------------------------------------------
__global__ __launch_bounds__(256) void fkan_naive(const float* __restrict__ x,
                                                  const float* __restrict__ coeffs,
                                                  const float* __restrict__ bias,
                                                  float* __restrict__ out) {
    const int b = blockIdx.x >> 1;
    const int o = ((blockIdx.x & 1) << 8) + threadIdx.x;
    float acc = bias[o];
    const float* xrow = x + (size_t)b * INDIM;
    for (int i = 0; i < INDIM; ++i) {
        const float rv = xrow[i] * INV2PI;
        const float cd = __builtin_amdgcn_cosf(rv);
        const float sd = __builtin_amdgcn_sinf(rv);
        float c = cd, s = sd;
        const float* cp = coeffs + (size_t)i * (KKDIM * OUTDIM) + o;
#pragma unroll 4
        for (int g = 0; g < NH; ++g) {
            acc += c * cp[g * 2 * OUTDIM] + s * cp[(g * 2 + 1) * OUTDIM];
            const float nc = c * cd - s * sd;
            const float ns = s * cd + c * sd;
            c = nc; s = ns;
        }
    }
    out[(size_t)b * OUTDIM + o] = acc;
}

extern "C" void kernel_launch(void* const* d_in, const int* in_sizes, int n_in,
                              void* d_out, int out_size, void* d_ws, size_t ws_size,
                              hipStream_t stream) {
    (void)in_sizes; (void)n_in; (void)out_size;
    const float* x      = (const float*)d_in[0];
    const float* coeffs = (const float*)d_in[1];
    const float* bias   = (const float*)d_in[2];
    float* out          = (float*)d_out;

    const size_t bt_bytes = (size_t)2 * INDIM * CHUNK_ELEMS * sizeof(unsigned short); // 32 MiB
    if (ws_size >= bt_bytes) {
        unsigned short* Bt = (unsigned short*)d_ws;
        fkan_prepass<<<2 * INDIM, 256, 0, stream>>>(coeffs, Bt);          // 1024 blocks
        fkan_bias_init<<<(BATCH * OUTDIM) / (4 * 256), 256, 0, stream>>>(bias, out);
        fkan_main<<<(BATCH / BM) * 2 * KSPLIT, THREADS, 0, stream>>>(x, Bt, out);  // 256 blocks
    } else {
        fkan_naive<<<BATCH * 2, 256, 0, stream>>>(x, coeffs, bias, out);
    }
}